// Round 2
// baseline (34089.169 us; speedup 1.0000x reference)
//
#include <hip/hip_runtime.h>
#include <hip/hip_cooperative_groups.h>
#include <math.h>

namespace cg = cooperative_groups;

#define NB 2048
#define NH 1024
#define DIN 1920
#define S_MAX 128
#define BAND 288

struct Scal {
  float t, dt, last_t, h0, d1, dt_used;
  int done, accept;
};

struct Ptrs {
  float *adj, *Acat, *y, *yp, *z;
  float *k[7];
  double *part;
  Scal *sc;
  float *out;
};

struct KArgs {
  Ptrs p;
  const float *feat; const int *sid; const float *mm;
  const float *Wp, *bp, *W1, *b1, *W2, *b2;
};

__device__ __constant__ float BETA[6][6] = {
  {(float)(1.0/5.0), 0.f, 0.f, 0.f, 0.f, 0.f},
  {(float)(3.0/40.0), (float)(9.0/40.0), 0.f, 0.f, 0.f, 0.f},
  {(float)(44.0/45.0), (float)(-56.0/15.0), (float)(32.0/9.0), 0.f, 0.f, 0.f},
  {(float)(19372.0/6561.0), (float)(-25360.0/2187.0), (float)(64448.0/6561.0), (float)(-212.0/729.0), 0.f, 0.f},
  {(float)(9017.0/3168.0), (float)(-355.0/33.0), (float)(46732.0/5247.0), (float)(49.0/176.0), (float)(-5103.0/18656.0), 0.f},
  {(float)(35.0/384.0), 0.f, (float)(500.0/1113.0), (float)(125.0/192.0), (float)(-2187.0/6784.0), (float)(11.0/84.0)}
};
__device__ __constant__ float CERR[7] = {
  (float)(35.0/384.0 - 1951.0/21600.0), 0.f,
  (float)(500.0/1113.0 - 22642.0/50085.0),
  (float)(125.0/192.0 - 451.0/720.0),
  (float)(-2187.0/6784.0 + 12231.0/42400.0),
  (float)(11.0/84.0 - 649.0/6300.0),
  (float)(-1.0/60.0)
};
__device__ __constant__ float CMID[7] = {
  (float)(6025192743.0/30085553152.0/2.0), 0.f,
  (float)(51252292925.0/65400821598.0/2.0),
  (float)(-2691868925.0/45128329728.0/2.0),
  (float)(187940372067.0/1594534317056.0/2.0),
  (float)(-1776094331.0/19743644256.0/2.0),
  (float)(11237099.0/235043384.0/2.0)
};

__device__ __forceinline__ int kmax(int a, int b) { return a > b ? a : b; }
__device__ __forceinline__ int kmin(int a, int b) { return a < b ? a : b; }

// 64x64 tile fp32 GEMM core: acc[16] = A[bm:bm+64, klo:khi] @ B[klo:khi, bn:bn+64]
__device__ __forceinline__ void gemm_tile(
    const float* __restrict__ A, int lda,
    const float* __restrict__ Bm, int ldb,
    int klo, int khi, int bm, int bn,
    float (*sa)[68], float (*sb)[68], float* acc)
{
  const int tid = threadIdx.x;
  const int arow = tid >> 2, ak = (tid & 3) << 2;
  const int bkr = tid >> 4, bc = (tid & 15) << 2;
  const int tx = tid & 15, ty = tid >> 4;
  const float* Ap = A + (size_t)(bm + arow) * lda + ak;
  const float* Bp = Bm + (size_t)bkr * ldb + bn + bc;
#pragma unroll
  for (int i = 0; i < 16; ++i) acc[i] = 0.f;
  for (int kk0 = klo; kk0 < khi; kk0 += 16) {
    float4 av = *(const float4*)(Ap + kk0);
    float4 bv = *(const float4*)(Bp + (size_t)kk0 * ldb);
    __syncthreads();
    sa[ak+0][arow] = av.x; sa[ak+1][arow] = av.y;
    sa[ak+2][arow] = av.z; sa[ak+3][arow] = av.w;
    *(float4*)&sb[bkr][bc] = bv;
    __syncthreads();
#pragma unroll
    for (int kk = 0; kk < 16; ++kk) {
      float4 a4 = *(const float4*)&sa[kk][ty << 2];
      float4 b4 = *(const float4*)&sb[kk][tx << 2];
      acc[0]  = fmaf(a4.x, b4.x, acc[0]);  acc[1]  = fmaf(a4.x, b4.y, acc[1]);
      acc[2]  = fmaf(a4.x, b4.z, acc[2]);  acc[3]  = fmaf(a4.x, b4.w, acc[3]);
      acc[4]  = fmaf(a4.y, b4.x, acc[4]);  acc[5]  = fmaf(a4.y, b4.y, acc[5]);
      acc[6]  = fmaf(a4.y, b4.z, acc[6]);  acc[7]  = fmaf(a4.y, b4.w, acc[7]);
      acc[8]  = fmaf(a4.z, b4.x, acc[8]);  acc[9]  = fmaf(a4.z, b4.y, acc[9]);
      acc[10] = fmaf(a4.z, b4.z, acc[10]); acc[11] = fmaf(a4.z, b4.w, acc[11]);
      acc[12] = fmaf(a4.w, b4.x, acc[12]); acc[13] = fmaf(a4.w, b4.y, acc[13]);
      acc[14] = fmaf(a4.w, b4.z, acc[14]); acc[15] = fmaf(a4.w, b4.w, acc[15]);
    }
  }
}

// ===================== persistent cooperative kernel =====================
__global__ __launch_bounds__(256, 2) void dgode(KArgs a)
{
  cg::grid_group grid = cg::this_grid();
  Ptrs p = a.p;
  volatile Scal* sc = (volatile Scal*)p.sc;
  const int gb = blockIdx.x, tid = threadIdx.x;
  const int bx = gb & 15, by = gb >> 4;
  const int bm = by << 6, bn = bx << 6;
  const int tx = tid & 15, ty = tid >> 4;
  const int m0 = bm + (ty << 2), n0 = bn + (tx << 2);

  __shared__ float sa[16][68];
  __shared__ float sb[16][68];
  __shared__ double red[256];
  __shared__ double red2[256];
  __shared__ float rowbuf[NB];

  float acc[16];

  if (gb == 0 && tid == 0) {
    sc->t = 0.f; sc->dt = 0.f; sc->last_t = 0.f; sc->h0 = 0.f;
    sc->d1 = 0.f; sc->dt_used = 0.f; sc->done = 0; sc->accept = 0;
  }

  // ---- adj build: 4 rows per block (bit-identical summation to round 1) ----
  for (int rr = 0; rr < 4; ++rr) {
    int i = (gb << 2) | rr;
    int si = a.sid[i];
    float mi0 = a.mm[3*i], mi1 = a.mm[3*i+1], mi2 = a.mm[3*i+2];
    double s = 0.0;
    for (int j = tid; j < NB; j += 256) {
      int dd = i - j; if (dd < 0) dd = -dd;
      float tw = expf(-0.1f * (float)dd);
      float ms = 1.0f - (fabsf(mi0 - a.mm[3*j]) + fabsf(mi1 - a.mm[3*j+1]) + fabsf(mi2 - a.mm[3*j+2])) / 3.0f;
      float v = (si == a.sid[j]) ? 0.8f * tw : 0.5f * tw * ms;
      if (j == i) v = 1.0f;
      rowbuf[j] = v;
      s += (double)v;
    }
    red[tid] = s; __syncthreads();
    for (int o = 128; o > 0; o >>= 1) { if (tid < o) red[tid] += red[tid+o]; __syncthreads(); }
    float den = (float)red[0] + 1e-8f;
    for (int j = tid; j < NB; j += 256) p.adj[(size_t)i*NB + j] = rowbuf[j] / den;
    __syncthreads();
  }

  // ---- h0 = feat @ Wp + bp  -> y, Acat-left ----
  gemm_tile(a.feat, DIN, a.Wp, NH, 0, DIN, bm, bn, sa, sb, acc);
#pragma unroll
  for (int i = 0; i < 4; ++i) {
    size_t ro = (size_t)(m0 + i) * NH + n0;
    size_t ao = (size_t)(m0 + i) * (2*NH) + n0;
#pragma unroll
    for (int j = 0; j < 4; ++j) {
      float v = acc[i*4+j] + a.bp[n0+j];
      p.y[ro+j] = v;
      p.Acat[ao+j] = v;
    }
  }
  grid.sync();

  // ---- one ODE-func evaluation: 3 GEMM phases; stage-dependent epilogue ----
  auto feval = [&](int stage, float* __restrict__ kt) {
    float dtv = sc->dt;
    // GEMM1: u = adj @ h  (banded: adj decays as e^{-0.1|i-j|})
    int klo = kmax(0, bm - BAND);
    int khi = kmin(NB, bm + 64 + BAND);
    gemm_tile(p.adj, NB, p.Acat, 2*NH, klo, khi, bm, bn, sa, sb, acc);
#pragma unroll
    for (int i = 0; i < 4; ++i) {
      size_t ao = (size_t)(m0 + i) * (2*NH) + NH + n0;
#pragma unroll
      for (int j = 0; j < 4; ++j) p.Acat[ao+j] = acc[i*4+j];
    }
    grid.sync();
    // GEMM2: z = tanh([h|u] @ W1 + b1)
    gemm_tile(p.Acat, 2*NH, a.W1, NH, 0, 2*NH, bm, bn, sa, sb, acc);
#pragma unroll
    for (int i = 0; i < 4; ++i) {
      size_t co = (size_t)(m0 + i) * NH + n0;
#pragma unroll
      for (int j = 0; j < 4; ++j) p.z[co+j] = tanhf(acc[i*4+j] + a.b1[n0+j]);
    }
    grid.sync();
    // GEMM3: k = z @ W2 + b2, plus dopri5 stage epilogue
    gemm_tile(p.z, NH, a.W2, NH, 0, NH, bm, bn, sa, sb, acc);
    double lsum = 0.0;
#pragma unroll
    for (int i = 0; i < 4; ++i) {
      size_t ro = (size_t)(m0 + i) * NH + n0;
      size_t ao = (size_t)(m0 + i) * (2*NH) + n0;
#pragma unroll
      for (int j = 0; j < 4; ++j) {
        float kv = acc[i*4+j] + a.b2[n0+j];
        kt[ro+j] = kv;
        if (stage >= 1 && stage <= 5) {
          float s_ = BETA[stage][0] * p.k[0][ro+j];
          if (stage >= 2) s_ = fmaf(BETA[stage][1], p.k[1][ro+j], s_);
          if (stage >= 3) s_ = fmaf(BETA[stage][2], p.k[2][ro+j], s_);
          if (stage >= 4) s_ = fmaf(BETA[stage][3], p.k[3][ro+j], s_);
          if (stage == 5) s_ = fmaf(BETA[stage][4], p.k[4][ro+j], s_);
          s_ = fmaf(BETA[stage][stage], kv, s_);
          p.Acat[ao+j] = p.y[ro+j] + dtv * s_;
        } else if (stage == 6) {
          float e_ = CERR[0] * p.k[0][ro+j];
          e_ = fmaf(CERR[2], p.k[2][ro+j], e_);
          e_ = fmaf(CERR[3], p.k[3][ro+j], e_);
          e_ = fmaf(CERR[4], p.k[4][ro+j], e_);
          e_ = fmaf(CERR[5], p.k[5][ro+j], e_);
          e_ = fmaf(CERR[6], kv, e_);
          float err = dtv * e_;
          float y0v = p.y[ro+j], y1v = p.Acat[ao+j];
          float tol = 1e-9f + 1e-7f * fmaxf(fabsf(y0v), fabsf(y1v));
          float r_ = err / tol;
          lsum += (double)r_ * (double)r_;
        }
      }
    }
    if (stage == 6) {
      red[tid] = lsum; __syncthreads();
      for (int o = 128; o > 0; o >>= 1) { if (tid < o) red[tid] += red[tid+o]; __syncthreads(); }
      if (tid == 0) p.part[gb] = red[0];
    }
    grid.sync();
  };

  auto norm_phase = [&](int which) {
    double s0 = 0.0, s1 = 0.0;
#pragma unroll
    for (int r = 0; r < 4; ++r) {
      int row = (gb << 2) | r; int col = tid << 2;
      size_t e = (size_t)row * NH + col;
#pragma unroll
      for (int j = 0; j < 4; ++j) {
        float yv = p.y[e+j];
        float scl = 1e-9f + 1e-7f * fabsf(yv);
        if (which == 0) {
          float aa = yv / scl, bb = p.k[0][e+j] / scl;
          s0 += (double)aa*aa; s1 += (double)bb*bb;
        } else {
          float aa = (p.k[1][e+j] - p.k[0][e+j]) / scl;
          s0 += (double)aa*aa;
        }
      }
    }
    red[tid] = s0; red2[tid] = s1; __syncthreads();
    for (int o = 128; o > 0; o >>= 1) {
      if (tid < o) { red[tid] += red[tid+o]; red2[tid] += red2[tid+o]; }
      __syncthreads();
    }
    if (tid == 0) { p.part[gb] = red[0]; if (which == 0) p.part[512 + gb] = red2[0]; }
    grid.sync();
  };

  auto form_phase = [&](int which) {
    float cf = (which == 0) ? sc->h0 : sc->dt * 0.2f;
#pragma unroll
    for (int r = 0; r < 4; ++r) {
      int row = (gb << 2) | r, col = tid << 2;
      size_t yi = (size_t)row * NH + col, ai = (size_t)row * (2*NH) + col;
      float4 yv = *(const float4*)(p.y + yi);
      float4 kv = *(const float4*)(p.k[0] + yi);
      float4 o;
      o.x = yv.x + cf*kv.x; o.y = yv.y + cf*kv.y;
      o.z = yv.z + cf*kv.z; o.w = yv.w + cf*kv.w;
      *(float4*)(p.Acat + ai) = o;
    }
    grid.sync();
  };

  // ---- initial step size (matches jax.experimental.ode heuristic) ----
  feval(0, p.k[0]);
  norm_phase(0);
  if (gb == 0) {
    red[tid]  = p.part[tid] + p.part[tid+256];
    red2[tid] = p.part[512+tid] + p.part[768+tid];
    __syncthreads();
    for (int o = 128; o > 0; o >>= 1) {
      if (tid < o) { red[tid] += red[tid+o]; red2[tid] += red2[tid+o]; }
      __syncthreads();
    }
    if (tid == 0) {
      float d0 = sqrtf((float)red[0]);
      float d1 = sqrtf((float)red2[0]);
      float h0 = (d0 < 1e-5f || d1 < 1e-5f) ? 1e-6f : 0.01f * d0 / d1;
      sc->h0 = h0; sc->d1 = d1;
    }
  }
  grid.sync();
  form_phase(0);
  feval(7, p.k[1]);
  norm_phase(1);
  if (gb == 0) {
    red[tid] = p.part[tid] + p.part[tid+256];
    __syncthreads();
    for (int o = 128; o > 0; o >>= 1) { if (tid < o) red[tid] += red[tid+o]; __syncthreads(); }
    if (tid == 0) {
      float h0 = sc->h0, d1 = sc->d1;
      float d2 = sqrtf((float)red[0]) / h0;
      float h1;
      if (d1 <= 1e-15f && d2 <= 1e-15f) h1 = fmaxf(1e-6f, h0 * 1e-3f);
      else h1 = powf(0.01f / fmaxf(d1, d2), 0.2f);
      sc->dt = fminf(100.f * h0, h1);
      sc->t = 0.f; sc->last_t = 0.f; sc->done = 0; sc->accept = 0;
    }
  }
  grid.sync();
  form_phase(1);

  // ---- adaptive dopri5 main loop (exits exactly at done) ----
  for (int it = 0; it < 256; ++it) {
    if (sc->done) break;
    feval(1, p.k[1]); feval(2, p.k[2]); feval(3, p.k[3]);
    feval(4, p.k[4]); feval(5, p.k[5]); feval(6, p.k[6]);
    if (gb == 0) {
      red[tid] = p.part[tid] + p.part[tid+256];
      __syncthreads();
      for (int o = 128; o > 0; o >>= 1) { if (tid < o) red[tid] += red[tid+o]; __syncthreads(); }
      if (tid == 0) {
        double mean = red[0] / (double)((size_t)NB*NH);
        float ratio = sqrtf((float)mean);
        float dtold = sc->dt;
        int acc_ = (ratio <= 1.0f) ? 1 : 0;
        float dfac = (ratio < 1.0f) ? 1.0f : 0.2f;
        float factor = fminf(10.0f, fmaxf(powf(ratio, -0.2f) * 0.9f, dfac));
        float dtnew = (ratio == 0.0f) ? dtold * 10.0f : dtold * factor;
        if (acc_) {
          sc->last_t = sc->t;
          sc->dt_used = dtold;
          float tn = sc->t + dtold;
          sc->t = tn;
          if (tn >= 1.0f) sc->done = 1;
        }
        sc->dt = dtnew;
        sc->accept = acc_;
      }
    }
    grid.sync();
    {
      int accept = sc->accept, done = sc->done;
      float dtn = sc->dt;
#pragma unroll
      for (int r = 0; r < 4; ++r) {
        int row = (gb << 2) | r, col = tid << 2;
        size_t yi = (size_t)row * NH + col, ai = (size_t)row * (2*NH) + col;
        if (accept) {
          float4 yo = *(const float4*)(p.y + yi);
          float4 y1 = *(const float4*)(p.Acat + ai);
          *(float4*)(p.yp + yi) = yo;
          *(float4*)(p.y + yi) = y1;
          if (!done) {
            float4 k6 = *(const float4*)(p.k[6] + yi);
            *(float4*)(p.k[0] + yi) = k6;
            float4 o;
            o.x = y1.x + dtn*0.2f*k6.x; o.y = y1.y + dtn*0.2f*k6.y;
            o.z = y1.z + dtn*0.2f*k6.z; o.w = y1.w + dtn*0.2f*k6.w;
            *(float4*)(p.Acat + ai) = o;
          }
        } else if (!done) {
          float4 yv = *(const float4*)(p.y + yi);
          float4 k0 = *(const float4*)(p.k[0] + yi);
          float4 o;
          o.x = yv.x + dtn*0.2f*k0.x; o.y = yv.y + dtn*0.2f*k0.y;
          o.z = yv.z + dtn*0.2f*k0.z; o.w = yv.w + dtn*0.2f*k0.w;
          *(float4*)(p.Acat + ai) = o;
        }
      }
    }
    grid.sync();
  }

  // ---- 4th-order interpolation to t=1 ----
  {
    float dtl = sc->dt_used;
    float rq = (1.0f - sc->last_t) / (sc->t - sc->last_t);
#pragma unroll
    for (int r = 0; r < 4; ++r) {
      int row = (gb << 2) | r, col = tid << 2;
      size_t base = (size_t)row * NH + col;
      for (int j = 0; j < 4; ++j) {
        size_t i2 = base + j;
        float y0 = p.yp[i2], y1 = p.y[i2], f0 = p.k[0][i2], f1 = p.k[6][i2];
        float md = CMID[0]*f0 + CMID[2]*p.k[2][i2] + CMID[3]*p.k[3][i2]
                 + CMID[4]*p.k[4][i2] + CMID[5]*p.k[5][i2] + CMID[6]*f1;
        float ym = y0 + dtl * md;
        float a_ = -2.f*dtl*f0 + 2.f*dtl*f1 -  8.f*y0 -  8.f*y1 + 16.f*ym;
        float b_ =  5.f*dtl*f0 - 3.f*dtl*f1 + 18.f*y0 + 14.f*y1 - 32.f*ym;
        float c_ = -4.f*dtl*f0 +     dtl*f1 - 11.f*y0 -  5.f*y1 + 16.f*ym;
        float d_ =      dtl*f0;
        p.out[i2] = (((a_*rq + b_)*rq + c_)*rq + d_)*rq + y0;
      }
    }
  }
}

// ===================== fallback path (round-1, known good) =====================
__global__ void init0(Ptrs p) {
  if (threadIdx.x == 0) {
    p.sc->t = 0.f; p.sc->dt = 0.f; p.sc->last_t = 0.f; p.sc->h0 = 0.f;
    p.sc->d1 = 0.f; p.sc->dt_used = 0.f; p.sc->done = 0; p.sc->accept = 0;
  }
}

__global__ __launch_bounds__(256) void adj_build(const int* __restrict__ sid,
                                                 const float* __restrict__ mm,
                                                 float* __restrict__ adj) {
  __shared__ float row[NB];
  __shared__ double rsum[256];
  int i = blockIdx.x, t = threadIdx.x;
  int si = sid[i];
  float mi0 = mm[3*i], mi1 = mm[3*i+1], mi2 = mm[3*i+2];
  double s = 0.0;
  for (int j = t; j < NB; j += 256) {
    float td = (float)abs(i - j);
    float tw = expf(-0.1f * td);
    float ms = 1.0f - (fabsf(mi0 - mm[3*j]) + fabsf(mi1 - mm[3*j+1]) + fabsf(mi2 - mm[3*j+2])) / 3.0f;
    float v = (si == sid[j]) ? 0.8f * tw : 0.5f * tw * ms;
    if (j == i) v = 1.0f;
    row[j] = v;
    s += (double)v;
  }
  rsum[t] = s; __syncthreads();
  for (int o = 128; o > 0; o >>= 1) { if (t < o) rsum[t] += rsum[t+o]; __syncthreads(); }
  float den = (float)rsum[0] + 1e-8f;
  for (int j = t; j < NB; j += 256) adj[(size_t)i*NB + j] = row[j] / den;
}

template<int MODE>
__global__ __launch_bounds__(256)
void gemm64(Ptrs p, const float* __restrict__ A, int lda,
            const float* __restrict__ Bm, int ldb,
            const float* __restrict__ bias,
            float* __restrict__ C, int ldc, int K, int stage)
{
  Scal* sc = p.sc;
  if (MODE != 0) { if (sc->done) return; }
  float dt = 0.f;
  if (MODE == 3) dt = sc->dt;

  __shared__ float sa[16][68];
  __shared__ float sb[16][68];
  __shared__ double red[256];

  int tid = threadIdx.x;
  int tx = tid & 15, ty = tid >> 4;
  int bn = blockIdx.x << 6, bm = blockIdx.y << 6;
  float acc[16];
  gemm_tile(A, lda, Bm, ldb, 0, K, bm, bn, sa, sb, acc);

  int m0 = bm + (ty << 2), n0 = bn + (tx << 2);
  if (MODE == 0) {
#pragma unroll
    for (int i = 0; i < 4; ++i) {
      size_t ro = (size_t)(m0 + i) * NH + n0;
      size_t ao = (size_t)(m0 + i) * (2*NH) + n0;
#pragma unroll
      for (int j = 0; j < 4; ++j) {
        float v = acc[i*4+j] + bias[n0+j];
        p.y[ro+j] = v;
        p.Acat[ao+j] = v;
      }
    }
  } else if (MODE == 1) {
#pragma unroll
    for (int i = 0; i < 4; ++i) {
      size_t co = (size_t)(m0 + i) * ldc + n0;
#pragma unroll
      for (int j = 0; j < 4; ++j) C[co+j] = acc[i*4+j];
    }
  } else if (MODE == 2) {
#pragma unroll
    for (int i = 0; i < 4; ++i) {
      size_t co = (size_t)(m0 + i) * ldc + n0;
#pragma unroll
      for (int j = 0; j < 4; ++j) C[co+j] = tanhf(acc[i*4+j] + bias[n0+j]);
    }
  } else {
    double lsum = 0.0;
#pragma unroll
    for (int i = 0; i < 4; ++i) {
      size_t ro = (size_t)(m0 + i) * NH + n0;
      size_t ao = (size_t)(m0 + i) * (2*NH) + n0;
#pragma unroll
      for (int j = 0; j < 4; ++j) {
        float kv = acc[i*4+j] + bias[n0+j];
        C[ro+j] = kv;
        if (stage >= 1 && stage <= 5) {
          float s_ = BETA[stage][0] * p.k[0][ro+j];
          if (stage >= 2) s_ = fmaf(BETA[stage][1], p.k[1][ro+j], s_);
          if (stage >= 3) s_ = fmaf(BETA[stage][2], p.k[2][ro+j], s_);
          if (stage >= 4) s_ = fmaf(BETA[stage][3], p.k[3][ro+j], s_);
          if (stage == 5) s_ = fmaf(BETA[stage][4], p.k[4][ro+j], s_);
          s_ = fmaf(BETA[stage][stage], kv, s_);
          p.Acat[ao+j] = p.y[ro+j] + dt * s_;
        } else if (stage == 6) {
          float e_ = CERR[0] * p.k[0][ro+j];
          e_ = fmaf(CERR[2], p.k[2][ro+j], e_);
          e_ = fmaf(CERR[3], p.k[3][ro+j], e_);
          e_ = fmaf(CERR[4], p.k[4][ro+j], e_);
          e_ = fmaf(CERR[5], p.k[5][ro+j], e_);
          e_ = fmaf(CERR[6], kv, e_);
          float err = dt * e_;
          float y0v = p.y[ro+j], y1v = p.Acat[ao+j];
          float tol = 1e-9f + 1e-7f * fmaxf(fabsf(y0v), fabsf(y1v));
          float r_ = err / tol;
          lsum += (double)r_ * (double)r_;
        }
      }
    }
    if (stage == 6) {
      red[tid] = lsum; __syncthreads();
      for (int o = 128; o > 0; o >>= 1) { if (tid < o) red[tid] += red[tid+o]; __syncthreads(); }
      if (tid == 0) p.part[blockIdx.y * gridDim.x + blockIdx.x] = red[0];
    }
  }
}

__global__ __launch_bounds__(256) void norm12(Ptrs p, int which) {
  __shared__ double red[256], red2[256];
  int tid = threadIdx.x;
  double s0 = 0.0, s1 = 0.0;
  for (size_t i = (size_t)blockIdx.x * 256 + tid; i < (size_t)NB*NH; i += 512*256) {
    float yv = p.y[i];
    float scl = 1e-9f + 1e-7f * fabsf(yv);
    if (which == 0) {
      float a = yv / scl, b = p.k[0][i] / scl;
      s0 += (double)a*a; s1 += (double)b*b;
    } else {
      float a = (p.k[1][i] - p.k[0][i]) / scl;
      s0 += (double)a*a;
    }
  }
  red[tid] = s0; red2[tid] = s1; __syncthreads();
  for (int o = 128; o > 0; o >>= 1) { if (tid < o) { red[tid]+=red[tid+o]; red2[tid]+=red2[tid+o]; } __syncthreads(); }
  if (tid == 0) { p.part[blockIdx.x] = red[0]; if (which == 0) p.part[512 + blockIdx.x] = red2[0]; }
}

__global__ __launch_bounds__(256) void ctrlA(Ptrs p) {
  __shared__ double red[256], red2[256];
  int tid = threadIdx.x;
  red[tid]  = p.part[tid] + p.part[tid+256];
  red2[tid] = p.part[512+tid] + p.part[768+tid];
  __syncthreads();
  for (int o = 128; o > 0; o >>= 1) { if (tid < o) { red[tid]+=red[tid+o]; red2[tid]+=red2[tid+o]; } __syncthreads(); }
  if (tid == 0) {
    float d0 = sqrtf((float)red[0]);
    float d1 = sqrtf((float)red2[0]);
    float h0 = (d0 < 1e-5f || d1 < 1e-5f) ? 1e-6f : 0.01f * d0 / d1;
    p.sc->h0 = h0; p.sc->d1 = d1;
  }
}

__global__ __launch_bounds__(256) void ctrlB(Ptrs p) {
  __shared__ double red[256];
  int tid = threadIdx.x;
  red[tid] = p.part[tid] + p.part[tid+256];
  __syncthreads();
  for (int o = 128; o > 0; o >>= 1) { if (tid < o) red[tid] += red[tid+o]; __syncthreads(); }
  if (tid == 0) {
    float h0 = p.sc->h0, d1 = p.sc->d1;
    float d2 = sqrtf((float)red[0]) / h0;
    float h1;
    if (d1 <= 1e-15f && d2 <= 1e-15f) h1 = fmaxf(1e-6f, h0 * 1e-3f);
    else h1 = powf(0.01f / fmaxf(d1, d2), 0.2f);
    p.sc->dt = fminf(100.f * h0, h1);
    p.sc->t = 0.f; p.sc->last_t = 0.f; p.sc->done = 0; p.sc->accept = 0;
  }
}

__global__ __launch_bounds__(256) void form_yi(Ptrs p, int which) {
  int row = blockIdx.x, c = threadIdx.x * 4;
  float cf = (which == 0) ? p.sc->h0 : p.sc->dt * 0.2f;
  size_t yi = (size_t)row * NH + c, ai = (size_t)row * (2*NH) + c;
  float4 yv = *(float4*)(p.y + yi);
  float4 kv = *(float4*)(p.k[0] + yi);
  float4 o;
  o.x = yv.x + cf*kv.x; o.y = yv.y + cf*kv.y; o.z = yv.z + cf*kv.z; o.w = yv.w + cf*kv.w;
  *(float4*)(p.Acat + ai) = o;
}

__global__ __launch_bounds__(256) void ctrl_step(Ptrs p) {
  Scal* sc = p.sc;
  if (sc->done) { if (threadIdx.x == 0) sc->accept = 0; return; }
  __shared__ double red[256];
  int tid = threadIdx.x;
  red[tid] = p.part[tid] + p.part[tid+256];
  __syncthreads();
  for (int o = 128; o > 0; o >>= 1) { if (tid < o) red[tid] += red[tid+o]; __syncthreads(); }
  if (tid == 0) {
    double mean = red[0] / (double)((size_t)NB*NH);
    float ratio = sqrtf((float)mean);
    float dtold = sc->dt;
    int acc_ = (ratio <= 1.0f) ? 1 : 0;
    float dfac = (ratio < 1.0f) ? 1.0f : 0.2f;
    float factor = fminf(10.0f, fmaxf(powf(ratio, -0.2f) * 0.9f, dfac));
    float dtnew = (ratio == 0.0f) ? dtold * 10.0f : dtold * factor;
    if (acc_) {
      sc->last_t = sc->t;
      sc->dt_used = dtold;
      float tn = sc->t + dtold;
      sc->t = tn;
      if (tn >= 1.0f) sc->done = 1;
    }
    sc->dt = dtnew;
    sc->accept = acc_;
  }
}

__global__ __launch_bounds__(256) void upd(Ptrs p) {
  Scal* sc = p.sc;
  int accept = sc->accept, done = sc->done;
  float dtn = sc->dt;
  int row = blockIdx.x, c = threadIdx.x * 4;
  size_t yi = (size_t)row * NH + c, ai = (size_t)row * (2*NH) + c;
  if (accept) {
    float4 yo = *(float4*)(p.y + yi);
    float4 y1 = *(float4*)(p.Acat + ai);
    *(float4*)(p.yp + yi) = yo;
    *(float4*)(p.y + yi) = y1;
    if (!done) {
      float4 k6 = *(float4*)(p.k[6] + yi);
      *(float4*)(p.k[0] + yi) = k6;
      float4 o;
      o.x = y1.x + dtn*0.2f*k6.x; o.y = y1.y + dtn*0.2f*k6.y;
      o.z = y1.z + dtn*0.2f*k6.z; o.w = y1.w + dtn*0.2f*k6.w;
      *(float4*)(p.Acat + ai) = o;
    }
  } else if (!done) {
    float4 yv = *(float4*)(p.y + yi);
    float4 k0 = *(float4*)(p.k[0] + yi);
    float4 o;
    o.x = yv.x + dtn*0.2f*k0.x; o.y = yv.y + dtn*0.2f*k0.y;
    o.z = yv.z + dtn*0.2f*k0.z; o.w = yv.w + dtn*0.2f*k0.w;
    *(float4*)(p.Acat + ai) = o;
  }
}

__global__ __launch_bounds__(256) void finalk(Ptrs p) {
  Scal* sc = p.sc;
  float dt = sc->dt_used;
  float r = (1.0f - sc->last_t) / (sc->t - sc->last_t);
  int row = blockIdx.x, c = threadIdx.x * 4;
  size_t base = (size_t)row * NH + c;
  for (int j = 0; j < 4; ++j) {
    size_t i = base + j;
    float y0 = p.yp[i], y1 = p.y[i], f0 = p.k[0][i], f1 = p.k[6][i];
    float md = CMID[0]*f0 + CMID[2]*p.k[2][i] + CMID[3]*p.k[3][i]
             + CMID[4]*p.k[4][i] + CMID[5]*p.k[5][i] + CMID[6]*f1;
    float ym = y0 + dt * md;
    float a  = -2.f*dt*f0 + 2.f*dt*f1 -  8.f*y0 -  8.f*y1 + 16.f*ym;
    float b  =  5.f*dt*f0 - 3.f*dt*f1 + 18.f*y0 + 14.f*y1 - 32.f*ym;
    float cc = -4.f*dt*f0 +     dt*f1 - 11.f*y0 -  5.f*y1 + 16.f*ym;
    float d  =      dt*f0;
    p.out[i] = (((a*r + b)*r + cc)*r + d)*r + y0;
  }
}

extern "C" void kernel_launch(void* const* d_in, const int* in_sizes, int n_in,
                              void* d_out, int out_size, void* d_ws, size_t ws_size,
                              hipStream_t stream) {
  (void)in_sizes; (void)n_in; (void)out_size; (void)ws_size;
  const float* feat = (const float*)d_in[0];
  const int*   sid  = (const int*)d_in[1];
  const float* mm   = (const float*)d_in[2];
  const float* Wp   = (const float*)d_in[3];
  const float* bp   = (const float*)d_in[4];
  const float* W1   = (const float*)d_in[5];
  const float* b1   = (const float*)d_in[6];
  const float* W2   = (const float*)d_in[7];
  const float* b2   = (const float*)d_in[8];

  float* W = (float*)d_ws;
  const size_t M1 = 1024 * 1024;
  Ptrs p;
  p.adj  = W;
  p.Acat = W + 4*M1;
  p.y    = W + 8*M1;
  p.yp   = W + 10*M1;
  p.z    = W + 12*M1;
  for (int s = 0; s < 7; ++s) p.k[s] = W + (14 + 2*(size_t)s)*M1;
  p.part = (double*)(W + 28*M1);
  p.sc   = (Scal*)(W + 28*M1 + 2048);
  p.out  = (float*)d_out;

  // -------- preferred path: single persistent cooperative kernel --------
  KArgs ka;
  ka.p = p; ka.feat = feat; ka.sid = sid; ka.mm = mm;
  ka.Wp = Wp; ka.bp = bp; ka.W1 = W1; ka.b1 = b1; ka.W2 = W2; ka.b2 = b2;
  void* kp[] = { &ka };
  hipError_t e = hipLaunchCooperativeKernel((const void*)dgode, dim3(512), dim3(256),
                                            kp, 0, stream);
  if (e == hipSuccess) return;
  (void)hipGetLastError();  // clear error state; fall back to multi-kernel path

  // -------- fallback path: round-1 multi-kernel sequence --------
  dim3 gg(NH/64, NB/64);
  init0<<<1, 64, 0, stream>>>(p);
  adj_build<<<NB, 256, 0, stream>>>(sid, mm, p.adj);
  gemm64<0><<<gg, 256, 0, stream>>>(p, feat, DIN, Wp, NH, bp, p.y, NH, DIN, 0);

  auto feval = [&](int stage, float* ktgt) {
    gemm64<1><<<gg, 256, 0, stream>>>(p, p.adj, NB, p.Acat, 2*NH, (const float*)nullptr, p.Acat + NH, 2*NH, NB, 0);
    gemm64<2><<<gg, 256, 0, stream>>>(p, p.Acat, 2*NH, W1, NH, b1, p.z, NH, 2*NH, 0);
    gemm64<3><<<gg, 256, 0, stream>>>(p, p.z, NH, W2, NH, b2, ktgt, NH, NH, stage);
  };

  feval(0, p.k[0]);
  norm12<<<512, 256, 0, stream>>>(p, 0);
  ctrlA<<<1, 256, 0, stream>>>(p);
  form_yi<<<NB, 256, 0, stream>>>(p, 0);
  feval(7, p.k[1]);
  norm12<<<512, 256, 0, stream>>>(p, 1);
  ctrlB<<<1, 256, 0, stream>>>(p);
  form_yi<<<NB, 256, 0, stream>>>(p, 1);

  for (int s = 0; s < S_MAX; ++s) {
    for (int st = 1; st <= 6; ++st) feval(st, p.k[st]);
    ctrl_step<<<1, 256, 0, stream>>>(p);
    upd<<<NB, 256, 0, stream>>>(p);
  }
  finalk<<<NB, 256, 0, stream>>>(p);
}

// Round 7
// 16408.044 us; speedup vs baseline: 2.0776x; 2.0776x over previous
//
#include <hip/hip_runtime.h>
#include <math.h>

#define NB 2048
#define NH 1024
#define DIN 1920
#define S_MAX 128
#define BAND 288
#define SCL 2048.0f
#define ISCL (1.0f/2048.0f)

typedef _Float16 f16;
typedef __attribute__((ext_vector_type(8))) _Float16 f16x8;
typedef __attribute__((ext_vector_type(4))) float f32x4;

struct Scal { float t, dt, last_t, h0, d1, dt_used; int done, accept; };

struct Ptrs {
  float *adj, *Acat, *y, *yp, *z;
  float *k[7];
  double *part;
  Scal *sc;
  float *out;
};

__device__ __constant__ float BETA[6][6] = {
  {(float)(1.0/5.0), 0.f, 0.f, 0.f, 0.f, 0.f},
  {(float)(3.0/40.0), (float)(9.0/40.0), 0.f, 0.f, 0.f, 0.f},
  {(float)(44.0/45.0), (float)(-56.0/15.0), (float)(32.0/9.0), 0.f, 0.f, 0.f},
  {(float)(19372.0/6561.0), (float)(-25360.0/2187.0), (float)(64448.0/6561.0), (float)(-212.0/729.0), 0.f, 0.f},
  {(float)(9017.0/3168.0), (float)(-355.0/33.0), (float)(46732.0/5247.0), (float)(49.0/176.0), (float)(-5103.0/18656.0), 0.f},
  {(float)(35.0/384.0), 0.f, (float)(500.0/1113.0), (float)(125.0/192.0), (float)(-2187.0/6784.0), (float)(11.0/84.0)}
};
__device__ __constant__ float CERR[7] = {
  (float)(35.0/384.0 - 1951.0/21600.0), 0.f,
  (float)(500.0/1113.0 - 22642.0/50085.0),
  (float)(125.0/192.0 - 451.0/720.0),
  (float)(-2187.0/6784.0 + 12231.0/42400.0),
  (float)(11.0/84.0 - 649.0/6300.0),
  (float)(-1.0/60.0)
};
__device__ __constant__ float CMID[7] = {
  (float)(6025192743.0/30085553152.0/2.0), 0.f,
  (float)(51252292925.0/65400821598.0/2.0),
  (float)(-2691868925.0/45128329728.0/2.0),
  (float)(187940372067.0/1594534317056.0/2.0),
  (float)(-1776094331.0/19743644256.0/2.0),
  (float)(11237099.0/235043384.0/2.0)
};

__device__ __forceinline__ int imax(int a, int b) { return a > b ? a : b; }
__device__ __forceinline__ int imin(int a, int b) { return a < b ? a : b; }

// ---------------- fp32 64x64 tile GEMM core (r1/r2 proven) ----------------
__device__ __forceinline__ void gemm_tile_f32(
    const float* __restrict__ A, int lda,
    const float* __restrict__ Bm, int ldb,
    int klo, int khi, int bm, int bn,
    float (*sa)[68], float (*sb)[68], float* acc, int tid)
{
  const int arow = tid >> 2, ak = (tid & 3) << 2;
  const int bkr = tid >> 4, bc = (tid & 15) << 2;
  const int tx = tid & 15, ty = tid >> 4;
  const float* Ap = A + (size_t)(bm + arow) * lda + ak;
  const float* Bp = Bm + (size_t)bkr * ldb + bn + bc;
#pragma unroll
  for (int i = 0; i < 16; ++i) acc[i] = 0.f;
  for (int kk0 = klo; kk0 < khi; kk0 += 16) {
    float4 av = *(const float4*)(Ap + kk0);
    float4 bv = *(const float4*)(Bp + (size_t)kk0 * ldb);
    __syncthreads();
    sa[ak+0][arow] = av.x; sa[ak+1][arow] = av.y;
    sa[ak+2][arow] = av.z; sa[ak+3][arow] = av.w;
    *(float4*)&sb[bkr][bc] = bv;
    __syncthreads();
#pragma unroll
    for (int kk = 0; kk < 16; ++kk) {
      float4 a4 = *(const float4*)&sa[kk][ty << 2];
      float4 b4 = *(const float4*)&sb[kk][tx << 2];
      acc[0]  = fmaf(a4.x, b4.x, acc[0]);  acc[1]  = fmaf(a4.x, b4.y, acc[1]);
      acc[2]  = fmaf(a4.x, b4.z, acc[2]);  acc[3]  = fmaf(a4.x, b4.w, acc[3]);
      acc[4]  = fmaf(a4.y, b4.x, acc[4]);  acc[5]  = fmaf(a4.y, b4.y, acc[5]);
      acc[6]  = fmaf(a4.y, b4.z, acc[6]);  acc[7]  = fmaf(a4.y, b4.w, acc[7]);
      acc[8]  = fmaf(a4.z, b4.x, acc[8]);  acc[9]  = fmaf(a4.z, b4.y, acc[9]);
      acc[10] = fmaf(a4.z, b4.z, acc[10]); acc[11] = fmaf(a4.z, b4.w, acc[11]);
      acc[12] = fmaf(a4.w, b4.x, acc[12]); acc[13] = fmaf(a4.w, b4.y, acc[13]);
      acc[14] = fmaf(a4.w, b4.z, acc[14]); acc[15] = fmaf(a4.w, b4.w, acc[15]);
    }
  }
}

__global__ void init0(Ptrs p) {
  if (threadIdx.x == 0) {
    p.sc->t = 0.f; p.sc->dt = 0.f; p.sc->last_t = 0.f; p.sc->h0 = 0.f;
    p.sc->d1 = 0.f; p.sc->dt_used = 0.f; p.sc->done = 0; p.sc->accept = 0;
  }
}

__global__ __launch_bounds__(256) void adj_build(const int* __restrict__ sid,
                                                 const float* __restrict__ mm,
                                                 float* __restrict__ adj) {
  __shared__ float row[NB];
  __shared__ double rsum[256];
  int i = blockIdx.x, t = threadIdx.x;
  int si = sid[i];
  float mi0 = mm[3*i], mi1 = mm[3*i+1], mi2 = mm[3*i+2];
  double s = 0.0;
  for (int j = t; j < NB; j += 256) {
    int dd = i - j; if (dd < 0) dd = -dd;
    float tw = expf(-0.1f * (float)dd);
    float ms = 1.0f - (fabsf(mi0 - mm[3*j]) + fabsf(mi1 - mm[3*j+1]) + fabsf(mi2 - mm[3*j+2])) / 3.0f;
    float v = (si == sid[j]) ? 0.8f * tw : 0.5f * tw * ms;
    if (j == i) v = 1.0f;
    row[j] = v;
    s += (double)v;
  }
  rsum[t] = s; __syncthreads();
  for (int o = 128; o > 0; o >>= 1) { if (t < o) rsum[t] += rsum[t+o]; __syncthreads(); }
  float den = (float)rsum[0] + 1e-8f;
  for (int j = t; j < NB; j += 256) adj[(size_t)i*NB + j] = row[j] / den;
}

// projection: y = Acat_left = feat @ Wp + bp   (r1 mode-0, verbatim logic)
__global__ __launch_bounds__(256)
void proj(Ptrs p, const float* __restrict__ feat, const float* __restrict__ Wp,
          const float* __restrict__ bp) {
  __shared__ float sa[16][68];
  __shared__ float sb[16][68];
  int tid = threadIdx.x;
  int bn = blockIdx.x << 6, bm = blockIdx.y << 6;
  float acc[16];
  gemm_tile_f32(feat, DIN, Wp, NH, 0, DIN, bm, bn, sa, sb, acc, tid);
  int m0 = bm + ((tid >> 4) << 2), n0 = bn + ((tid & 15) << 2);
#pragma unroll
  for (int i = 0; i < 4; ++i) {
    size_t ro = (size_t)(m0 + i) * NH + n0;
    size_t ao = (size_t)(m0 + i) * (2*NH) + n0;
#pragma unroll
    for (int j = 0; j < 4; ++j) {
      float v = acc[i*4+j] + bp[n0+j];
      p.y[ro+j] = v;
      p.Acat[ao+j] = v;
    }
  }
}

// Phase A: Acat_right = adj @ Acat_left, band-limited K (r2-proven logic)
__global__ __launch_bounds__(256)
void gemmA(Ptrs p) {
  if (p.sc->done) return;
  __shared__ float sa[16][68];
  __shared__ float sb[16][68];
  int tid = threadIdx.x;
  int bn = blockIdx.x << 6, bm = blockIdx.y << 6;
  int klo = imax(0, bm - BAND), khi = imin(NB, bm + 64 + BAND);
  float acc[16];
  gemm_tile_f32(p.adj, NB, p.Acat, 2*NH, klo, khi, bm, bn, sa, sb, acc, tid);
  int m0 = bm + ((tid >> 4) << 2), n0 = bn + ((tid & 15) << 2);
#pragma unroll
  for (int i = 0; i < 4; ++i) {
    size_t co = (size_t)(m0 + i) * (2*NH) + NH + n0;
#pragma unroll
    for (int j = 0; j < 4; ++j) p.Acat[co+j] = acc[i*4+j];
  }
}

// ---------------- f16 split-precision MFMA tile core (NON-swapped) ----------------
// value = accM + ISCL*accL = Asrc[tm0:+64, 0:K] @ W[0:K, tn0:+64]
// Asrc: fp32 rows (contiguous k), split on stage. W: fp32 [K][ldw], transposed into LDS.
__device__ __forceinline__ void mfma_tile(
    int tm0, int tn0, int K,
    const float* __restrict__ Asrc, int lda,
    const float* __restrict__ Wsrc, int ldw,
    f16* __restrict__ sm, f32x4 accM[2][2], f32x4 accL[2][2], int tid)
{
  const int quad = tid & 3, srow = tid >> 2;       // A staging map
  const int kk = tid >> 4, ng = tid & 15;          // W staging map
  const int lane = tid & 63, llo = lane & 15, lhi = lane >> 4;
  const int wv = tid >> 6, wr = wv >> 1, wc = wv & 1;
  f16* saH = sm;         f16* saL = sm + 2080;
  f16* sbH = sm + 4160;  f16* sbL = sm + 6240;

  const float* abase = Asrc + (size_t)(tm0 + srow) * lda + quad*8;
  const float* wbase = Wsrc + (size_t)kk * ldw + tn0 + ng*4;
  const int afr_s = (wr*32 + llo) * 8;
  const int bfr_s = (wc*32 + llo) * 8;
  const int qA = kk >> 3, eA = kk & 7;

  for (int k0 = 0; k0 < K; k0 += 32) {
    // A: 8 consecutive k of row (tm0+srow)
    float4 qa0 = *(const float4*)(abase + k0);
    float4 qa1 = *(const float4*)(abase + k0 + 4);
    // W: rows k0+kk and k0+16+kk, 4 consecutive n
    const float* wp = wbase + (size_t)k0 * ldw;
    float4 qw0 = *(const float4*)wp;
    float4 qw1 = *(const float4*)(wp + (size_t)16 * ldw);

    f16x8 ah, al;
    { float v;
      v=qa0.x; ah[0]=(f16)v; al[0]=(f16)((v-(float)ah[0])*SCL);
      v=qa0.y; ah[1]=(f16)v; al[1]=(f16)((v-(float)ah[1])*SCL);
      v=qa0.z; ah[2]=(f16)v; al[2]=(f16)((v-(float)ah[2])*SCL);
      v=qa0.w; ah[3]=(f16)v; al[3]=(f16)((v-(float)ah[3])*SCL);
      v=qa1.x; ah[4]=(f16)v; al[4]=(f16)((v-(float)ah[4])*SCL);
      v=qa1.y; ah[5]=(f16)v; al[5]=(f16)((v-(float)ah[5])*SCL);
      v=qa1.z; ah[6]=(f16)v; al[6]=(f16)((v-(float)ah[6])*SCL);
      v=qa1.w; ah[7]=(f16)v; al[7]=(f16)((v-(float)ah[7])*SCL);
    }
    __syncthreads();
    *(f16x8*)(saH + quad*520 + srow*8) = ah;
    *(f16x8*)(saL + quad*520 + srow*8) = al;
    {
      f16* bH0 = sbH + qA*520 + ng*32 + eA;
      f16* bL0 = sbL + qA*520 + ng*32 + eA;
      f16* bH1 = sbH + (qA+2)*520 + ng*32 + eA;
      f16* bL1 = sbL + (qA+2)*520 + ng*32 + eA;
      float v; f16 hv;
      v=qw0.x; hv=(f16)v; bH0[0]  = hv; bL0[0]  = (f16)((v-(float)hv)*SCL);
      v=qw0.y; hv=(f16)v; bH0[8]  = hv; bL0[8]  = (f16)((v-(float)hv)*SCL);
      v=qw0.z; hv=(f16)v; bH0[16] = hv; bL0[16] = (f16)((v-(float)hv)*SCL);
      v=qw0.w; hv=(f16)v; bH0[24] = hv; bL0[24] = (f16)((v-(float)hv)*SCL);
      v=qw1.x; hv=(f16)v; bH1[0]  = hv; bL1[0]  = (f16)((v-(float)hv)*SCL);
      v=qw1.y; hv=(f16)v; bH1[8]  = hv; bL1[8]  = (f16)((v-(float)hv)*SCL);
      v=qw1.z; hv=(f16)v; bH1[16] = hv; bL1[16] = (f16)((v-(float)hv)*SCL);
      v=qw1.w; hv=(f16)v; bH1[24] = hv; bL1[24] = (f16)((v-(float)hv)*SCL);
    }
    __syncthreads();
    f16x8 aH0 = *(const f16x8*)(saH + lhi*520 + afr_s);
    f16x8 aH1 = *(const f16x8*)(saH + lhi*520 + afr_s + 128);
    f16x8 aL0 = *(const f16x8*)(saL + lhi*520 + afr_s);
    f16x8 aL1 = *(const f16x8*)(saL + lhi*520 + afr_s + 128);
    f16x8 bH0 = *(const f16x8*)(sbH + lhi*520 + bfr_s);
    f16x8 bH1 = *(const f16x8*)(sbH + lhi*520 + bfr_s + 128);
    f16x8 bL0 = *(const f16x8*)(sbL + lhi*520 + bfr_s);
    f16x8 bL1 = *(const f16x8*)(sbL + lhi*520 + bfr_s + 128);

    accM[0][0] = __builtin_amdgcn_mfma_f32_16x16x32_f16(aH0, bH0, accM[0][0], 0,0,0);
    accM[0][1] = __builtin_amdgcn_mfma_f32_16x16x32_f16(aH0, bH1, accM[0][1], 0,0,0);
    accM[1][0] = __builtin_amdgcn_mfma_f32_16x16x32_f16(aH1, bH0, accM[1][0], 0,0,0);
    accM[1][1] = __builtin_amdgcn_mfma_f32_16x16x32_f16(aH1, bH1, accM[1][1], 0,0,0);
    accL[0][0] = __builtin_amdgcn_mfma_f32_16x16x32_f16(aH0, bL0, accL[0][0], 0,0,0);
    accL[0][0] = __builtin_amdgcn_mfma_f32_16x16x32_f16(aL0, bH0, accL[0][0], 0,0,0);
    accL[0][1] = __builtin_amdgcn_mfma_f32_16x16x32_f16(aH0, bL1, accL[0][1], 0,0,0);
    accL[0][1] = __builtin_amdgcn_mfma_f32_16x16x32_f16(aL0, bH1, accL[0][1], 0,0,0);
    accL[1][0] = __builtin_amdgcn_mfma_f32_16x16x32_f16(aH1, bL0, accL[1][0], 0,0,0);
    accL[1][0] = __builtin_amdgcn_mfma_f32_16x16x32_f16(aL1, bH0, accL[1][0], 0,0,0);
    accL[1][1] = __builtin_amdgcn_mfma_f32_16x16x32_f16(aH1, bL1, accL[1][1], 0,0,0);
    accL[1][1] = __builtin_amdgcn_mfma_f32_16x16x32_f16(aL1, bH1, accL[1][1], 0,0,0);
  }
}

// Phase B: z = tanh(Acat @ W1 + b1)
__global__ __launch_bounds__(256, 2)
void gemmB(Ptrs p, const float* __restrict__ W1, const float* __restrict__ b1) {
  if (p.sc->done) return;
  __shared__ __align__(16) f16 sm[8320];
  int tid = threadIdx.x, gb = blockIdx.x;
  int tm0 = (gb >> 4) << 6, tn0 = (gb & 15) << 6;
  f32x4 accM[2][2] = {}, accL[2][2] = {};
  mfma_tile(tm0, tn0, 2*NH, p.Acat, 2*NH, W1, NH, sm, accM, accL, tid);
  const int lane = tid & 63, llo = lane & 15, lhi = lane >> 4;
  const int wv = tid >> 6, wr = wv >> 1, wc = wv & 1;
  int rowb = tm0 + wr*32 + lhi*4, colb = tn0 + wc*32 + llo;
#pragma unroll
  for (int fm = 0; fm < 2; ++fm)
#pragma unroll
  for (int fn = 0; fn < 2; ++fn)
#pragma unroll
  for (int r = 0; r < 4; ++r) {
    int row = rowb + fm*16 + r, col = colb + fn*16;
    float val = fmaf(ISCL, accL[fm][fn][r], accM[fm][fn][r]);
    p.z[(size_t)row*NH + col] = tanhf(val + b1[col]);
  }
}

// Phase C: kt = z @ W2 + b2, + dopri5 stage epilogue (r1 logic, per-element)
__global__ __launch_bounds__(256, 2)
void gemmC(Ptrs p, const float* __restrict__ W2, const float* __restrict__ b2,
           float* __restrict__ kt, int stage) {
  if (p.sc->done) return;
  float dt = p.sc->dt;
  __shared__ __align__(16) f16 sm[8320];
  __shared__ double red[256];
  int tid = threadIdx.x, gb = blockIdx.x;
  int tm0 = (gb >> 4) << 6, tn0 = (gb & 15) << 6;
  f32x4 accM[2][2] = {}, accL[2][2] = {};
  mfma_tile(tm0, tn0, NH, p.z, NH, W2, NH, sm, accM, accL, tid);
  const int lane = tid & 63, llo = lane & 15, lhi = lane >> 4;
  const int wv = tid >> 6, wr = wv >> 1, wc = wv & 1;
  int rowb = tm0 + wr*32 + lhi*4, colb = tn0 + wc*32 + llo;
  double lsum = 0.0;
#pragma unroll
  for (int fm = 0; fm < 2; ++fm)
#pragma unroll
  for (int fn = 0; fn < 2; ++fn)
#pragma unroll
  for (int r = 0; r < 4; ++r) {
    int row = rowb + fm*16 + r, col = colb + fn*16;
    size_t ro = (size_t)row * NH + col;
    size_t ao = (size_t)row * (2*NH) + col;
    float kv = fmaf(ISCL, accL[fm][fn][r], accM[fm][fn][r]) + b2[col];
    kt[ro] = kv;
    if (stage >= 1 && stage <= 5) {
      float s_ = BETA[stage][0] * p.k[0][ro];
      if (stage >= 2) s_ = fmaf(BETA[stage][1], p.k[1][ro], s_);
      if (stage >= 3) s_ = fmaf(BETA[stage][2], p.k[2][ro], s_);
      if (stage >= 4) s_ = fmaf(BETA[stage][3], p.k[3][ro], s_);
      if (stage == 5) s_ = fmaf(BETA[stage][4], p.k[4][ro], s_);
      s_ = fmaf(BETA[stage][stage], kv, s_);
      p.Acat[ao] = p.y[ro] + dt * s_;
    } else if (stage == 6) {
      float e_ = CERR[0] * p.k[0][ro];
      e_ = fmaf(CERR[2], p.k[2][ro], e_);
      e_ = fmaf(CERR[3], p.k[3][ro], e_);
      e_ = fmaf(CERR[4], p.k[4][ro], e_);
      e_ = fmaf(CERR[5], p.k[5][ro], e_);
      e_ = fmaf(CERR[6], kv, e_);
      float err = dt * e_;
      float y0v = p.y[ro], y1v = p.Acat[ao];
      float tol = 1e-9f + 1e-7f * fmaxf(fabsf(y0v), fabsf(y1v));
      float r_ = err / tol;
      lsum += (double)r_ * (double)r_;
    }
  }
  if (stage == 6) {
    red[tid] = lsum; __syncthreads();
    for (int o = 128; o > 0; o >>= 1) { if (tid < o) red[tid] += red[tid+o]; __syncthreads(); }
    if (tid == 0) p.part[gb] = red[0];
  }
}

__global__ __launch_bounds__(256) void norm12(Ptrs p, int which) {
  __shared__ double red[256], red2[256];
  int tid = threadIdx.x;
  double s0 = 0.0, s1 = 0.0;
  for (size_t i = (size_t)blockIdx.x * 256 + tid; i < (size_t)NB*NH; i += 512*256) {
    float yv = p.y[i];
    float scl = 1e-9f + 1e-7f * fabsf(yv);
    if (which == 0) {
      float a = yv / scl, b = p.k[0][i] / scl;
      s0 += (double)a*a; s1 += (double)b*b;
    } else {
      float a = (p.k[1][i] - p.k[0][i]) / scl;
      s0 += (double)a*a;
    }
  }
  red[tid] = s0; red2[tid] = s1; __syncthreads();
  for (int o = 128; o > 0; o >>= 1) { if (tid < o) { red[tid]+=red[tid+o]; red2[tid]+=red2[tid+o]; } __syncthreads(); }
  if (tid == 0) { p.part[blockIdx.x] = red[0]; if (which == 0) p.part[512 + blockIdx.x] = red2[0]; }
}

__global__ __launch_bounds__(256) void ctrlA(Ptrs p) {
  __shared__ double red[256], red2[256];
  int tid = threadIdx.x;
  red[tid]  = p.part[tid] + p.part[tid+256];
  red2[tid] = p.part[512+tid] + p.part[768+tid];
  __syncthreads();
  for (int o = 128; o > 0; o >>= 1) { if (tid < o) { red[tid]+=red[tid+o]; red2[tid]+=red2[tid+o]; } __syncthreads(); }
  if (tid == 0) {
    float d0 = sqrtf((float)red[0]);
    float d1 = sqrtf((float)red2[0]);
    float h0 = (d0 < 1e-5f || d1 < 1e-5f) ? 1e-6f : 0.01f * d0 / d1;
    p.sc->h0 = h0; p.sc->d1 = d1;
  }
}

__global__ __launch_bounds__(256) void ctrlB(Ptrs p) {
  __shared__ double red[256];
  int tid = threadIdx.x;
  red[tid] = p.part[tid] + p.part[tid+256];
  __syncthreads();
  for (int o = 128; o > 0; o >>= 1) { if (tid < o) red[tid] += red[tid+o]; __syncthreads(); }
  if (tid == 0) {
    float h0 = p.sc->h0, d1 = p.sc->d1;
    float d2 = sqrtf((float)red[0]) / h0;
    float h1;
    if (d1 <= 1e-15f && d2 <= 1e-15f) h1 = fmaxf(1e-6f, h0 * 1e-3f);
    else h1 = powf(0.01f / fmaxf(d1, d2), 0.2f);
    p.sc->dt = fminf(100.f * h0, h1);
    p.sc->t = 0.f; p.sc->last_t = 0.f; p.sc->done = 0; p.sc->accept = 0;
  }
}

__global__ __launch_bounds__(256) void form_yi(Ptrs p, int which) {
  int row = blockIdx.x, c = threadIdx.x * 4;
  float cf = (which == 0) ? p.sc->h0 : p.sc->dt * 0.2f;
  size_t yi = (size_t)row * NH + c, ai = (size_t)row * (2*NH) + c;
  float4 yv = *(float4*)(p.y + yi);
  float4 kv = *(float4*)(p.k[0] + yi);
  float4 o;
  o.x = yv.x + cf*kv.x; o.y = yv.y + cf*kv.y; o.z = yv.z + cf*kv.z; o.w = yv.w + cf*kv.w;
  *(float4*)(p.Acat + ai) = o;
}

__global__ __launch_bounds__(256) void ctrl_step(Ptrs p) {
  Scal* sc = p.sc;
  if (sc->done) { if (threadIdx.x == 0) sc->accept = 0; return; }
  __shared__ double red[256];
  int tid = threadIdx.x;
  red[tid] = p.part[tid] + p.part[tid+256];
  __syncthreads();
  for (int o = 128; o > 0; o >>= 1) { if (tid < o) red[tid] += red[tid+o]; __syncthreads(); }
  if (tid == 0) {
    double mean = red[0] / (double)((size_t)NB*NH);
    float ratio = sqrtf((float)mean);
    float dtold = sc->dt;
    int acc_ = (ratio <= 1.0f) ? 1 : 0;
    float dfac = (ratio < 1.0f) ? 1.0f : 0.2f;
    float factor = fminf(10.0f, fmaxf(powf(ratio, -0.2f) * 0.9f, dfac));
    float dtnew = (ratio == 0.0f) ? dtold * 10.0f : dtold * factor;
    if (acc_) {
      sc->last_t = sc->t;
      sc->dt_used = dtold;
      float tn = sc->t + dtold;
      sc->t = tn;
      if (tn >= 1.0f) sc->done = 1;
    }
    sc->dt = dtnew;
    sc->accept = acc_;
  }
}

__global__ __launch_bounds__(256) void upd(Ptrs p) {
  Scal* sc = p.sc;
  int accept = sc->accept, done = sc->done;
  float dtn = sc->dt;
  int row = blockIdx.x, c = threadIdx.x * 4;
  size_t yi = (size_t)row * NH + c, ai = (size_t)row * (2*NH) + c;
  if (accept) {
    float4 yo = *(float4*)(p.y + yi);
    float4 y1 = *(float4*)(p.Acat + ai);
    *(float4*)(p.yp + yi) = yo;
    *(float4*)(p.y + yi) = y1;
    if (!done) {
      float4 k6 = *(float4*)(p.k[6] + yi);
      *(float4*)(p.k[0] + yi) = k6;
      float4 o;
      o.x = y1.x + dtn*0.2f*k6.x; o.y = y1.y + dtn*0.2f*k6.y;
      o.z = y1.z + dtn*0.2f*k6.z; o.w = y1.w + dtn*0.2f*k6.w;
      *(float4*)(p.Acat + ai) = o;
    }
  } else if (!done) {
    float4 yv = *(float4*)(p.y + yi);
    float4 k0 = *(float4*)(p.k[0] + yi);
    float4 o;
    o.x = yv.x + dtn*0.2f*k0.x; o.y = yv.y + dtn*0.2f*k0.y;
    o.z = yv.z + dtn*0.2f*k0.z; o.w = yv.w + dtn*0.2f*k0.w;
    *(float4*)(p.Acat + ai) = o;
  }
}

__global__ __launch_bounds__(256) void finalk(Ptrs p) {
  Scal* sc = p.sc;
  float dt = sc->dt_used;
  float r = (1.0f - sc->last_t) / (sc->t - sc->last_t);
  int row = blockIdx.x, c = threadIdx.x * 4;
  size_t base = (size_t)row * NH + c;
  for (int j = 0; j < 4; ++j) {
    size_t i = base + j;
    float y0 = p.yp[i], y1 = p.y[i], f0 = p.k[0][i], f1 = p.k[6][i];
    float md = CMID[0]*f0 + CMID[2]*p.k[2][i] + CMID[3]*p.k[3][i]
             + CMID[4]*p.k[4][i] + CMID[5]*p.k[5][i] + CMID[6]*f1;
    float ym = y0 + dt * md;
    float a  = -2.f*dt*f0 + 2.f*dt*f1 -  8.f*y0 -  8.f*y1 + 16.f*ym;
    float b  =  5.f*dt*f0 - 3.f*dt*f1 + 18.f*y0 + 14.f*y1 - 32.f*ym;
    float cc = -4.f*dt*f0 +     dt*f1 - 11.f*y0 -  5.f*y1 + 16.f*ym;
    float d  =      dt*f0;
    p.out[i] = (((a*r + b)*r + cc)*r + d)*r + y0;
  }
}

extern "C" void kernel_launch(void* const* d_in, const int* in_sizes, int n_in,
                              void* d_out, int out_size, void* d_ws, size_t ws_size,
                              hipStream_t stream) {
  (void)in_sizes; (void)n_in; (void)out_size; (void)ws_size;
  const float* feat = (const float*)d_in[0];
  const int*   sid  = (const int*)d_in[1];
  const float* mm   = (const float*)d_in[2];
  const float* Wp   = (const float*)d_in[3];
  const float* bp   = (const float*)d_in[4];
  const float* W1   = (const float*)d_in[5];
  const float* b1   = (const float*)d_in[6];
  const float* W2   = (const float*)d_in[7];
  const float* b2   = (const float*)d_in[8];

  // layout byte-identical to round 1 (proven fits in ws)
  float* W = (float*)d_ws;
  const size_t M1 = 1024 * 1024;
  Ptrs p;
  p.adj  = W;
  p.Acat = W + 4*M1;
  p.y    = W + 8*M1;
  p.yp   = W + 10*M1;
  p.z    = W + 12*M1;
  for (int s = 0; s < 7; ++s) p.k[s] = W + (14 + 2*(size_t)s)*M1;
  p.part = (double*)(W + 28*M1);
  p.sc   = (Scal*)(W + 28*M1 + 2048);
  p.out  = (float*)d_out;

  dim3 gg(NH/64, NB/64);

  init0<<<1, 64, 0, stream>>>(p);
  adj_build<<<NB, 256, 0, stream>>>(sid, mm, p.adj);
  proj<<<gg, 256, 0, stream>>>(p, feat, Wp, bp);

  auto feval = [&](int stage, float* ktgt) {
    gemmA<<<gg, 256, 0, stream>>>(p);
    gemmB<<<512, 256, 0, stream>>>(p, W1, b1);
    gemmC<<<512, 256, 0, stream>>>(p, W2, b2, ktgt, stage);
  };

  feval(0, p.k[0]);
  norm12<<<512, 256, 0, stream>>>(p, 0);
  ctrlA<<<1, 256, 0, stream>>>(p);
  form_yi<<<NB, 256, 0, stream>>>(p, 0);
  feval(7, p.k[1]);
  norm12<<<512, 256, 0, stream>>>(p, 1);
  ctrlB<<<1, 256, 0, stream>>>(p);
  form_yi<<<NB, 256, 0, stream>>>(p, 1);

  for (int s = 0; s < S_MAX; ++s) {
    for (int st = 1; st <= 6; ++st) feval(st, p.k[st]);
    ctrl_step<<<1, 256, 0, stream>>>(p);
    upd<<<NB, 256, 0, stream>>>(p);
  }
  finalk<<<NB, 256, 0, stream>>>(p);
}